// Round 9
// baseline (331.317 us; speedup 1.0000x reference)
//
#include <hip/hip_runtime.h>
#include <stdint.h>

#define HH 80
#define WW 80
#define CC 64
#define BB 32
#define NDIAG (HH + WW - 1)   // 159
#define SLICE (HH * WW * CC)  // 409600 f16 per (dir,b) scratch slice

typedef _Float16 f16;
typedef _Float16 f16x8 __attribute__((ext_vector_type(8)));
typedef _Float16 f16x4 __attribute__((ext_vector_type(4)));
typedef float floatx4 __attribute__((ext_vector_type(4)));

struct GPtrs { const float* p[8]; };

// ---------------------------------------------------------------------------
// Layouts carried unchanged from the PASSING round-7/8 kernels:
// sigma storage order (xT, scratch): position p = 16q + 8h + jj holds channel
//   c = 32h + 8q + jj (lane (q,l15) owns one 32B run per cell).
// A-row permutation phi'(cb,m) = 32*(cb>>1) + 8*(m>>2) + 4*(cb&1) + (m&3)
//   makes MFMA D layout == next-diag B layout (h never leaves registers).
// Pairing (R7-verified): Av(gv) x BU(up neighbor), Ah(gh) x P(left neighbor).
// ROUND-9 CHANGE: ONE WAVE OWNS THE WHOLE PROBLEM (all 80 cells = 5 tiles in
// its own registers). The cross-tile up-neighbor (lane15 of tile t-1 ->
// lane0 of tile t) is a DPP row_shl:15 + cndmask — all-register. ZERO LDS,
// ZERO barriers, ZERO flags in the dag kernel. R8's counters showed the
// inter-wave LDS handoff (~500+cy/diag) was the floor; this deletes it.
// ---------------------------------------------------------------------------

// Pre-pass: x[b][c][i][j] (f32) -> xT[((b*H+i)*W+j)*C + p] (f16, sigma order).
__global__ __launch_bounds__(256) void xpose_kernel(const float* __restrict__ x,
                                                    f16* __restrict__ xT) {
  const int bi = blockIdx.x;            // b*HH + i
  const int b = bi / HH, i = bi - b * HH;
  __shared__ float tile[WW][CC + 1];    // [j][c], stride 65
  const float* xp = x + ((size_t)(b * CC) * HH + i) * WW;  // + c*(H*W) + j
  for (int idx = threadIdx.x; idx < CC * WW; idx += 256) {
    const int c = idx / WW, j = idx - c * WW;   // consecutive j -> coalesced
    tile[j][c] = xp[(size_t)c * (HH * WW) + j];
  }
  __syncthreads();
  f16* op = xT + (size_t)(b * HH + i) * WW * CC;
  for (int idx = threadIdx.x; idx < (WW * CC) / 4; idx += 256) {
    const int j = idx >> 4, m = idx & 15;       // positions 4m..4m+3
    const int cbase = 32 * ((m >> 1) & 1) + 8 * (m >> 2) + 4 * (m & 1);
    f16x4 v;
    v[0] = (f16)tile[j][cbase + 0];
    v[1] = (f16)tile[j][cbase + 1];
    v[2] = (f16)tile[j][cbase + 2];
    v[3] = (f16)tile[j][cbase + 3];
    *(f16x4*)(op + j * CC + m * 4) = v;         // 128B contiguous per 16 lanes
  }
}

__device__ inline f16x8 dpp_shr1(f16x8 v) {   // lane i <- lane i-1 (16-row), 0-fill
  union { f16x8 h; int i[4]; } s, r;
  s.h = v;
#pragma unroll
  for (int k = 0; k < 4; ++k)
    r.i[k] = __builtin_amdgcn_update_dpp(0, s.i[k], 0x111, 0xF, 0xF, true);
  return r.h;
}

__device__ inline f16x8 dpp_shl15(f16x8 v) {  // lane 16r+0 <- lane 16r+15, 0 elsewhere
  union { f16x8 h; int i[4]; } s, r;
  s.h = v;
#pragma unroll
  for (int k = 0; k < 4; ++k)
    r.i[k] = __builtin_amdgcn_update_dpp(0, s.i[k], 0x10F, 0xF, 0xF, true);
  return r.h;
}

__device__ inline floatx4 MF(f16x8 a, f16x8 b, floatx4 c) {
  return __builtin_amdgcn_mfma_f32_16x16x32_f16(a, b, c, 0, 0, 0);
}

// ---------------------------------------------------------------------------
// Main kernel: 128 blocks x 64 threads. ONE wave per (dir,b) problem.
// Per diagonal d: for each active tile t (descending, so P[t-1] is still the
// previous diagonal's pack when tile t reads it):
//   BU = dpp_shr1(P[t]); lane0 <- dpp_shl15(P[t-1])      (up neighbor)
//   a  = mfma(Ah0,P[t]0, mfma(Ah1,P[t]1, mfma(Av0,BU0, mfma(Av1,BU1, 0))))
//   r  = pk_add_f16(cvt_f16(a), X[t]); relu; P[t] = ok ? r : 0
//   store P[t] to scratch (2x dwordx2-f16, fire-and-forget)
// then prefetch X for d+2 (guarded by d+2's tile range; depth-2 ring XA/XB).
// Addressing is affine: cell index = cbase[t] + (fj ? -d : +d), clamped for
// loads (inactive lanes), exact for stores (ok-masked lanes only).
// ---------------------------------------------------------------------------
__global__ __launch_bounds__(64, 1) void dag_kernel(const f16* __restrict__ xT,
                                                    GPtrs g,
                                                    f16* __restrict__ scratch) {
  const int blk = blockIdx.x;   // 0..127
  const int dir = blk >> 5;     // 0:SE 1:NE 2:NW 3:SW
  const int b   = blk & 31;
  const int lane = threadIdx.x & 63;
  const int l15  = lane & 15;   // cell-in-tile (MFMA n / D col)
  const int q    = lane >> 4;   // quad (D row-quad / B k-quad)
  const int q16  = q * 16;

  const bool fi      = (dir == 1) || (dir == 2);  // flip i
  const bool fj      = (dir == 2) || (dir == 3);  // flip j
  const bool do_relu = (dir != 3);                // SW scan has no ReLU
  const float* __restrict__ gv = g.p[2 * dir];
  const float* __restrict__ gh = g.p[2 * dir + 1];

  const f16* const xTb = xT + (size_t)b * SLICE;
  f16* const sbase = scratch + (size_t)blk * SLICE;

  // gamma A fragments with phi' row permutation (verified R7/R8).
  f16x8 Av[4][2], Ah[4][2];
#pragma unroll
  for (int cb = 0; cb < 4; ++cb) {
    const int row = 32 * (cb >> 1) + 8 * (l15 >> 2) + 4 * (cb & 1) + (l15 & 3);
    const float* pv = gv + row * CC;
    const float* ph = gh + row * CC;
#pragma unroll
    for (int jj = 0; jj < 8; ++jj) {
      Av[cb][0][jj] = (f16)pv[q * 8 + jj];
      Av[cb][1][jj] = (f16)pv[32 + q * 8 + jj];
      Ah[cb][0][jj] = (f16)ph[q * 8 + jj];
      Ah[cb][1][jj] = (f16)ph[32 + q * 8 + jj];
    }
  }

  // per-tile affine address base: cell(t,d) = cbase[t] + (fj ? -d : +d)
  int cbase[5];
#pragma unroll
  for (int t = 0; t < 5; ++t) {
    const int ip = t * 16 + l15;
    const int io = fi ? (HH - 1 - ip) : ip;
    cbase[t] = io * WW + (fj ? (WW - 1 + ip) : -ip);
  }

  f16x8 P[5][2];                 // h packs (prev diagonal); h[-1] = 0
  {
    const f16x8 z = {};
#pragma unroll
    for (int t = 0; t < 5; ++t) { P[t][0] = z; P[t][1] = z; }
  }

  f16x8 XA[5][2], XB[5][2];      // x seeds, depth-2 parity ring
  {  // prologue: diag 0 -> XA (tile 0 only), diag 1 -> XB (tile 0 only)
    const int c0 = min(max(cbase[0], 0), HH * WW - 1);
    const f16* xp0 = xTb + (((size_t)c0) << 6) + q16;
    XA[0][0] = *(const f16x8*)xp0;  XA[0][1] = *(const f16x8*)(xp0 + 8);
    const int c1 = min(max(cbase[0] + (fj ? -1 : 1), 0), HH * WW - 1);
    const f16* xp1 = xTb + (((size_t)c1) << 6) + q16;
    XB[0][0] = *(const f16x8*)xp1;  XB[0][1] = *(const f16x8*)(xp1 + 8);
  }

  auto step = [&](int d, f16x8 (&X)[5][2]) {
    const int lo = max(0, d - (WW - 1));
    const int hi = min(d, HH - 1);
    const int tlo = lo >> 4, thi = hi >> 4;
    const int sd = fj ? -d : d;
    const int d2 = min(d + 2, NDIAG - 1);
    const int lo2 = max(0, d2 - (WW - 1));
    const int hi2 = min(d2, HH - 1);
    const int tlo2 = lo2 >> 4, thi2 = hi2 >> 4;
    const int sd2 = fj ? -d2 : d2;

    // tiles DESCENDING so tile t reads P[t-1] before tile t-1 updates it
#define DO_TILE(T)                                                             \
    if (tlo <= (T) && (T) <= thi) {                                            \
      f16x8 BU0 = dpp_shr1(P[(T)][0]);                                         \
      f16x8 BU1 = dpp_shr1(P[(T)][1]);                                         \
      if ((T) > 0) {                                                           \
        const f16x8 in0 = dpp_shl15(P[(T) > 0 ? (T) - 1 : 0][0]);              \
        const f16x8 in1 = dpp_shl15(P[(T) > 0 ? (T) - 1 : 0][1]);              \
        BU0 = (l15 == 0) ? in0 : BU0;                                          \
        BU1 = (l15 == 0) ? in1 : BU1;                                          \
      }                                                                        \
      floatx4 a0 = {0.f, 0.f, 0.f, 0.f}, a1 = a0, a2 = a0, a3 = a0;            \
      a0 = MF(Ah[0][0], P[(T)][0], a0); a1 = MF(Ah[1][0], P[(T)][0], a1);      \
      a2 = MF(Ah[2][0], P[(T)][0], a2); a3 = MF(Ah[3][0], P[(T)][0], a3);      \
      a0 = MF(Ah[0][1], P[(T)][1], a0); a1 = MF(Ah[1][1], P[(T)][1], a1);      \
      a2 = MF(Ah[2][1], P[(T)][1], a2); a3 = MF(Ah[3][1], P[(T)][1], a3);      \
      a0 = MF(Av[0][0], BU0, a0);       a1 = MF(Av[1][0], BU0, a1);            \
      a2 = MF(Av[2][0], BU0, a2);       a3 = MF(Av[3][0], BU0, a3);            \
      a0 = MF(Av[0][1], BU1, a0);       a1 = MF(Av[1][1], BU1, a1);            \
      a2 = MF(Av[2][1], BU1, a2);       a3 = MF(Av[3][1], BU1, a3);            \
      f16x8 r0, r1;                                                            \
      _Pragma("unroll")                                                        \
      for (int r = 0; r < 4; ++r) {                                            \
        r0[r] = (f16)a0[r]; r0[4 + r] = (f16)a1[r];                            \
        r1[r] = (f16)a2[r]; r1[4 + r] = (f16)a3[r];                            \
      }                                                                        \
      r0 = r0 + X[(T)][0];   /* x added post-MFMA: v_pk_add_f16 */             \
      r1 = r1 + X[(T)][1];                                                     \
      if (do_relu) {                                                           \
        _Pragma("unroll")                                                      \
        for (int e = 0; e < 8; ++e) {                                          \
          r0[e] = (r0[e] > (f16)0.f) ? r0[e] : (f16)0.f;                       \
          r1[e] = (r1[e] > (f16)0.f) ? r1[e] : (f16)0.f;                       \
        }                                                                      \
      }                                                                        \
      const bool ok = (l15 >= lo - (T) * 16) && (l15 <= hi - (T) * 16);        \
      const f16x8 zz = {};                                                     \
      P[(T)][0] = ok ? r0 : zz;                                                \
      P[(T)][1] = ok ? r1 : zz;                                                \
      if (ok) {                                                                \
        f16* so = sbase + (((size_t)(cbase[(T)] + sd)) << 6) + q16;            \
        *(f16x8*)so       = P[(T)][0];                                         \
        *(f16x8*)(so + 8) = P[(T)][1];                                         \
      }                                                                        \
    }
    DO_TILE(4) DO_TILE(3) DO_TILE(2) DO_TILE(1) DO_TILE(0)
#undef DO_TILE

    // prefetch x for d+2 (guard = d+2's tile range; clamp keeps addr in-slice)
#define PF(T)                                                                  \
    if (tlo2 <= (T) && (T) <= thi2) {                                          \
      const int ci = min(max(cbase[(T)] + sd2, 0), HH * WW - 1);               \
      const f16* xp = xTb + (((size_t)ci) << 6) + q16;                         \
      X[(T)][0] = *(const f16x8*)xp;                                           \
      X[(T)][1] = *(const f16x8*)(xp + 8);                                     \
    }
    PF(0) PF(1) PF(2) PF(3) PF(4)
#undef PF
  };

  for (int d = 0; d < NDIAG - 1; d += 2) {   // 158 is even -> tail below
    step(d,     XA);
    step(d + 1, XB);
  }
  step(NDIAG - 1, XA);
}

// ---------------------------------------------------------------------------
// Reduce: out[b][c][i][j] = sum over 4 dirs of scratch[dir][b][i][j][p],
// un-permuting sigma: group k holds channels c0 = 32*(k&1) + 8*(k>>1) .. +7.
// ---------------------------------------------------------------------------
__global__ __launch_bounds__(256) void reduce_kernel(const f16* __restrict__ s,
                                                     float* __restrict__ out) {
  const int bi = blockIdx.x;            // b*HH + i
  const int b = bi / HH, i = bi - b * HH;
  __shared__ float tile[WW][CC + 1];    // [j][c], stride 65
  const size_t dstride = (size_t)BB * SLICE;
  const f16* p = s + (size_t)b * SLICE + (size_t)i * (WW * CC);
  for (int idx = threadIdx.x; idx < (WW * CC) / 8; idx += 256) {  // 640
    const int j = idx >> 3, k = idx & 7;
    const size_t off = (size_t)j * CC + k * 8;
    const f16x8 a0 = *(const f16x8*)(p + off);
    const f16x8 a1 = *(const f16x8*)(p + off + dstride);
    const f16x8 a2 = *(const f16x8*)(p + off + 2 * dstride);
    const f16x8 a3 = *(const f16x8*)(p + off + 3 * dstride);
    const int c0 = 32 * (k & 1) + 8 * (k >> 1);
#pragma unroll
    for (int t = 0; t < 8; ++t)
      tile[j][c0 + t] = (float)a0[t] + (float)a1[t] + (float)a2[t] + (float)a3[t];
  }
  __syncthreads();
  float* op = out + ((size_t)(b * CC) * HH + i) * WW;  // + c*(H*W) + j
  const int c  = threadIdx.x >> 2;        // 0..63
  const int jb = (threadIdx.x & 3) * 4;   // 0,4,8,12
#pragma unroll
  for (int k = 0; k < 5; ++k) {
    const int j0 = jb + k * 16;
    floatx4 v;
    v[0] = tile[j0 + 0][c];
    v[1] = tile[j0 + 1][c];
    v[2] = tile[j0 + 2][c];
    v[3] = tile[j0 + 3][c];
    *(floatx4*)(op + (size_t)c * (HH * WW) + j0) = v;  // 64B per 4 lanes
  }
}

// ---------------------------------------------------------------------------
extern "C" void kernel_launch(void* const* d_in, const int* in_sizes, int n_in,
                              void* d_out, int out_size, void* d_ws, size_t ws_size,
                              hipStream_t stream) {
  const float* x = (const float*)d_in[0];
  GPtrs g;
  for (int k = 0; k < 8; ++k) g.p[k] = (const float*)d_in[k + 1];  // g1,g2,g4,g5,g7,g8,g10,g11
  f16* xT = (f16*)d_ws;                         // 26.2 MB
  f16* scratch = xT + (size_t)BB * SLICE;       // 104.9 MB

  xpose_kernel<<<BB * HH, 256, 0, stream>>>(x, xT);
  dag_kernel<<<4 * BB, 64, 0, stream>>>((const f16*)xT, g, scratch);
  reduce_kernel<<<BB * HH, 256, 0, stream>>>((const f16*)scratch, (float*)d_out);
}